// Round 1
// baseline (2195.424 us; speedup 1.0000x reference)
//
#include <hip/hip_runtime.h>
#include <hip/hip_bf16.h>

// GNN layer restructured:
//   A = nf @ We1[0:128,:]      [N,256]
//   B = nf @ We1[128:256,:]    [N,256]
//   C = ef @ We1[256:320,:]    [E,256]   (chunked to cap workspace)
//   H[d] += lrelu(A[s]+B[d]+C[e]); H[s] += lrelu(A[d]+B[s]+C[e])   (edge pass, fp32 atomics)
//   red = H @ We2              [N,128]   (We2 pulled out of segment-sum: linearity)
//   hid = lrelu([nf|red] @ Wn1)[N,256]
//   out = hid @ Wn2            [N,128]

#define BK 64
#define XPAD 68   // row stride for transposed X tile: 16B-aligned (mult of 4), 8-way store conflict accepted

__device__ __forceinline__ float lrelu(float x) { return x >= 0.f ? x : 0.01f * x; }

// out[N,M] = cat(X1[N,K1], X2[N,K2]) @ W[(K1+K2), ldw] (cols col0..col0+63 of W)
// Requires K1 % BK == 0 (true for all call sites: 128, 256, 64, 128).
__global__ __launch_bounds__(256) void gemm_cat(
    const float* __restrict__ X1, int K1,
    const float* __restrict__ X2, int K2,
    const float* __restrict__ W, int ldw,
    float* __restrict__ out, int N, int M, int do_lrelu)
{
    __shared__ float xs[BK][XPAD];   // transposed: xs[k][row]
    __shared__ float wsm[BK][64];    // wsm[k][col]

    const int row0 = blockIdx.x * 64;
    const int col0 = blockIdx.y * 64;
    const int tid  = threadIdx.x;
    const int K    = K1 + K2;
    const int tr   = tid >> 4;   // 0..15 -> rows tr*4..tr*4+3
    const int tc   = tid & 15;   // 0..15 -> cols tc*4..tc*4+3

    float acc[4][4] = {};

    for (int k0 = 0; k0 < K; k0 += BK) {
        const float* Xsrc;
        int kloc, ksz;
        if (k0 < K1) { Xsrc = X1; kloc = k0;      ksz = K1; }
        else         { Xsrc = X2; kloc = k0 - K1; ksz = K2; }

        // load X tile (64 rows x BK), store transposed
        #pragma unroll
        for (int it = 0; it < 16; ++it) {
            int idx = tid + it * 256;
            int r  = idx >> 6;       // 0..63
            int kk = idx & 63;
            int row = row0 + r;
            float v = 0.f;
            if (row < N) v = Xsrc[(size_t)row * ksz + kloc + kk];
            xs[kk][r] = v;
        }
        // load W tile (BK x 64)
        #pragma unroll
        for (int it = 0; it < 16; ++it) {
            int idx = tid + it * 256;
            int kk = idx >> 6;
            int c  = idx & 63;
            wsm[kk][c] = W[(size_t)(k0 + kk) * ldw + col0 + c];
        }
        __syncthreads();

        #pragma unroll 8
        for (int kk = 0; kk < BK; ++kk) {
            float4 a = *reinterpret_cast<const float4*>(&xs[kk][tr * 4]);
            float4 b = *reinterpret_cast<const float4*>(&wsm[kk][tc * 4]);
            float av[4] = {a.x, a.y, a.z, a.w};
            float bv[4] = {b.x, b.y, b.z, b.w};
            #pragma unroll
            for (int i = 0; i < 4; ++i)
                #pragma unroll
                for (int j = 0; j < 4; ++j)
                    acc[i][j] += av[i] * bv[j];
        }
        __syncthreads();
    }

    #pragma unroll
    for (int i = 0; i < 4; ++i) {
        int row = row0 + tr * 4 + i;
        if (row >= N) continue;
        float4 v = make_float4(acc[i][0], acc[i][1], acc[i][2], acc[i][3]);
        if (do_lrelu) {
            v.x = lrelu(v.x); v.y = lrelu(v.y); v.z = lrelu(v.z); v.w = lrelu(v.w);
        }
        *reinterpret_cast<float4*>(&out[(size_t)row * M + col0 + tc * 4]) = v;
    }
}

// one block (256 thr) per undirected edge; handles both directions
__global__ __launch_bounds__(256) void edge_pass(
    const float* __restrict__ A, const float* __restrict__ B,
    const float* __restrict__ C,
    const int* __restrict__ src, const int* __restrict__ dst,
    float* __restrict__ H, int e0, int e1)
{
    int e = e0 + blockIdx.x;
    if (e >= e1) return;
    int j = threadIdx.x;            // feature index 0..255
    int s = src[e], d = dst[e];
    float c  = C[(size_t)(e - e0) * 256 + j];
    float as = A[(size_t)s * 256 + j];
    float bd = B[(size_t)d * 256 + j];
    float ad = A[(size_t)d * 256 + j];
    float bs = B[(size_t)s * 256 + j];
    float hf = lrelu(as + bd + c);
    float hb = lrelu(ad + bs + c);
    atomicAdd(&H[(size_t)d * 256 + j], hf);
    atomicAdd(&H[(size_t)s * 256 + j], hb);
}

extern "C" void kernel_launch(void* const* d_in, const int* in_sizes, int n_in,
                              void* d_out, int out_size, void* d_ws, size_t ws_size,
                              hipStream_t stream) {
    const float* nf  = (const float*)d_in[0];
    const float* ef  = (const float*)d_in[1];
    const int*   src = (const int*)d_in[2];
    const int*   dst = (const int*)d_in[3];
    const float* We1 = (const float*)d_in[4];   // [320,256]
    const float* We2 = (const float*)d_in[5];   // [256,128]
    const float* Wn1 = (const float*)d_in[6];   // [256,256]
    const float* Wn2 = (const float*)d_in[7];   // [256,128]
    float* out = (float*)d_out;

    const int N = in_sizes[0] / 128;            // 100000
    const int E = in_sizes[2];                  // 500000

    // workspace layout (floats)
    float* A   = (float*)d_ws;
    float* Bb  = A   + (size_t)N * 256;
    float* H   = Bb  + (size_t)N * 256;
    float* red = H   + (size_t)N * 256;
    float* Cb  = red + (size_t)N * 128;
    float* hid = A;                             // reuse: A dead after edge pass

    size_t base_floats = (size_t)N * 256 * 3 + (size_t)N * 128;
    long long avail = (long long)(ws_size / 4) - (long long)base_floats;
    int chunk = 65536;
    if (avail < (long long)chunk * 256) {
        chunk = (int)(avail / 256);
        if (chunk < 1024) chunk = 1024;         // last-resort; assume ws is big enough
    }

    dim3 blk(256);

    // A = nf @ We1[0:128,:], B = nf @ We1[128:256,:]
    {
        dim3 grid((N + 63) / 64, 4);
        gemm_cat<<<grid, blk, 0, stream>>>(nf, 128, nullptr, 0, We1,            256, A,  N, 256, 0);
        gemm_cat<<<grid, blk, 0, stream>>>(nf, 128, nullptr, 0, We1 + 128 * 256, 256, Bb, N, 256, 0);
    }

    hipMemsetAsync(H, 0, (size_t)N * 256 * sizeof(float), stream);

    // chunked: C = ef[e0:e1] @ We1[256:320,:], then edge pass
    for (int e0 = 0; e0 < E; e0 += chunk) {
        int ce = E - e0 < chunk ? E - e0 : chunk;
        dim3 gridc((ce + 63) / 64, 4);
        gemm_cat<<<gridc, blk, 0, stream>>>(ef + (size_t)e0 * 64, 64, nullptr, 0,
                                            We1 + 256 * 256, 256, Cb, ce, 256, 0);
        edge_pass<<<dim3(ce), blk, 0, stream>>>(A, Bb, Cb, src, dst, H, e0, e0 + ce);
    }

    // red = H @ We2
    {
        dim3 grid((N + 63) / 64, 2);
        gemm_cat<<<grid, blk, 0, stream>>>(H, 256, nullptr, 0, We2, 128, red, N, 128, 0);
    }
    // hid = lrelu([nf|red] @ Wn1)
    {
        dim3 grid((N + 63) / 64, 4);
        gemm_cat<<<grid, blk, 0, stream>>>(nf, 128, red, 128, Wn1, 256, hid, N, 256, 1);
    }
    // out = hid @ Wn2
    {
        dim3 grid((N + 63) / 64, 2);
        gemm_cat<<<grid, blk, 0, stream>>>(hid, 256, nullptr, 0, Wn2, 128, out, N, 128, 0);
    }
}